// Round 1
// 816.250 us; speedup vs baseline: 1.2763x; 1.2763x over previous
//
#include <hip/hip_runtime.h>
#include <math.h>

// Problem constants
#define BB    2
#define NN    1024
#define CC    768
#define HH    12
#define HPP   24
#define HD    64
#define SCALE 0.125f

typedef float fvec4 __attribute__((ext_vector_type(4)));

// workspace layout (floats)
#define SEG   (2*1024*768)   // 1,572,864 floats per tensor
#define QOFF  0              // q_tok: (B*N, 768) token-major
#define KOFF  (SEG)          // k_t:   (B, 768, N) transposed
#define VOFF  (2*SEG)        // v:     (B, H, N, HD)
#define HOFF  (3*SEG)        // head_out: (B, N, C)

// ---------------------------------------------------------------------------
// Kernel 1: fused QKV projection.  x(2048,768) @ [Wqk;Wv]^T.
// Epilogue scatters: q -> token-major rows, k -> transposed (b,p,n), v -> (b,h,n,d).
// ---------------------------------------------------------------------------
__global__ __launch_bounds__(256)
void qkv_gemm(const float* __restrict__ x, const float* __restrict__ Wqk,
              const float* __restrict__ Wv, float* __restrict__ ws)
{
    __shared__ float As[16][68];   // [k][m], +4 pad keeps 16B alignment
    __shared__ float Bs[16][68];
    float* qtok = ws + QOFF;
    float* kt   = ws + KOFF;
    float* vws  = ws + VOFF;

    const int tid  = threadIdx.x;
    const int bn   = blockIdx.x;        // 0..35 (2304 cols / 64)
    const int bm   = blockIdx.y;        // 0..31 (2048 rows / 64)
    const int tx   = tid & 15, ty = tid >> 4;
    const int lrow = tid >> 2;          // 0..63
    const int lk   = (tid & 3) << 2;    // 0,4,8,12

    const int jrow = bn * 64 + lrow;    // weight row (output column)
    const float* Bsrc = (jrow < 1536) ? (Wqk + (size_t)jrow * 768)
                                      : (Wv  + (size_t)(jrow - 1536) * 768);
    const float* Asrc = x + (size_t)(bm * 64 + lrow) * 768;

    float c[4][4] = {};

    for (int k0 = 0; k0 < 768; k0 += 16) {
        float4 av = *(const float4*)(Asrc + k0 + lk);
        float4 bv = *(const float4*)(Bsrc + k0 + lk);
        __syncthreads();
        As[lk+0][lrow] = av.x; As[lk+1][lrow] = av.y;
        As[lk+2][lrow] = av.z; As[lk+3][lrow] = av.w;
        Bs[lk+0][lrow] = bv.x; Bs[lk+1][lrow] = bv.y;
        Bs[lk+2][lrow] = bv.z; Bs[lk+3][lrow] = bv.w;
        __syncthreads();
#pragma unroll
        for (int kk = 0; kk < 16; ++kk) {
            float a[4], b[4];
#pragma unroll
            for (int i = 0; i < 4; ++i) a[i] = As[kk][ty*4 + i];
#pragma unroll
            for (int j = 0; j < 4; ++j) b[j] = Bs[kk][tx*4 + j];
#pragma unroll
            for (int i = 0; i < 4; ++i)
#pragma unroll
                for (int j = 0; j < 4; ++j)
                    c[i][j] = fmaf(a[i], b[j], c[i][j]);
        }
    }

#pragma unroll
    for (int i = 0; i < 4; ++i) {
        const int t = bm*64 + ty*4 + i;      // token index 0..2047
        const int b = t >> 10, n = t & 1023;
#pragma unroll
        for (int j = 0; j < 4; ++j) {
            const int col = bn*64 + tx*4 + j;
            const float val = c[i][j];
            if (col < 768) {
                qtok[(size_t)t*768 + col] = val;
            } else if (col < 1536) {
                const int p = col - 768;                 // h*64+d
                kt[((size_t)(b*768 + p))*NN + n] = val;  // transposed
            } else {
                const int p = col - 1536;
                vws[(((size_t)b*HH + (p >> 6))*NN + n)*HD + (p & 63)] = val;
            }
        }
    }
}

// ---------------------------------------------------------------------------
// Kernel 2 (v3): per block = 2 consecutive tokens (b, n0), (b, n0+1).
// Each K float4 load feeds BOTH tokens' logit accumulation (register reuse,
// halves cache read traffic).  XCD pinning: blockIdx&7 selects the XCD slot;
// bit2 = batch so each XCD's L2 only holds one batch's K (3 MB < 4 MB).
// A_exp written with non-temporal stores so the 201 MB stream doesn't evict K.
// ---------------------------------------------------------------------------
__global__ __launch_bounds__(256, 4)
void attn_expand(const float* __restrict__ qtok, const float* __restrict__ kt,
                 const float* __restrict__ Wexp, float* __restrict__ aexp)
{
    __shared__ __align__(16) float qs[2*CC];     // 6 KB: q rows for both tokens
    __shared__ float wexp_s[HPP * HH];           // 1.2 KB
    __shared__ float smax[2][HH * 4];
    __shared__ float ssum[2][HH * 4];

    const int tid  = threadIdx.x;
    const int lane = tid & 63, wid = tid >> 6;
    const int x    = blockIdx.x & 7;             // XCD slot (round-robin dispatch)
    const int b    = x >> 2;                     // batch pinned per XCD half
    const int np   = ((x & 3) << 7) | (blockIdx.x >> 3);   // token-pair 0..511
    const int n0   = np << 1;
    const int m4   = tid;                        // float4 column index 0..255

    const fvec4* qsrc = (const fvec4*)(qtok + (size_t)(b*NN + n0) * CC);
    ((fvec4*)qs)[tid] = qsrc[tid];
    if (tid < 128) ((fvec4*)qs)[256 + tid] = qsrc[256 + tid];
    for (int i2 = tid; i2 < HPP*HH; i2 += 256) wexp_s[i2] = Wexp[i2];
    __syncthreads();

    // ---- logits for both tokens: one K load -> 8 FMAs --------------------
    fvec4 l0[HH], l1[HH];
#pragma unroll
    for (int h = 0; h < HH; ++h) {
        fvec4 a0 = {0.f,0.f,0.f,0.f}, a1 = {0.f,0.f,0.f,0.f};
        const fvec4* kr = ((const fvec4*)kt) + (size_t)(b*768 + h*64) * 256 + m4;
        const float* q0p = qs + h*64;
        const float* q1p = qs + CC + h*64;
#pragma unroll 8
        for (int d = 0; d < 64; ++d) {
            const fvec4 kv = kr[(size_t)d * 256];
            const float qa = q0p[d];
            const float qb = q1p[d];
            a0.x = fmaf(kv.x, qa, a0.x); a0.y = fmaf(kv.y, qa, a0.y);
            a0.z = fmaf(kv.z, qa, a0.z); a0.w = fmaf(kv.w, qa, a0.w);
            a1.x = fmaf(kv.x, qb, a1.x); a1.y = fmaf(kv.y, qb, a1.y);
            a1.z = fmaf(kv.z, qb, a1.z); a1.w = fmaf(kv.w, qb, a1.w);
        }
        l0[h].x = a0.x*SCALE; l0[h].y = a0.y*SCALE;
        l0[h].z = a0.z*SCALE; l0[h].w = a0.w*SCALE;
        l1[h].x = a1.x*SCALE; l1[h].y = a1.y*SCALE;
        l1[h].z = a1.z*SCALE; l1[h].w = a1.w*SCALE;
    }

    // ---- softmax over m for each token/head ------------------------------
#pragma unroll
    for (int h = 0; h < HH; ++h) {
        float t0 = fmaxf(fmaxf(l0[h].x, l0[h].y), fmaxf(l0[h].z, l0[h].w));
        float t1 = fmaxf(fmaxf(l1[h].x, l1[h].y), fmaxf(l1[h].z, l1[h].w));
#pragma unroll
        for (int off = 32; off > 0; off >>= 1) {
            t0 = fmaxf(t0, __shfl_xor(t0, off, 64));
            t1 = fmaxf(t1, __shfl_xor(t1, off, 64));
        }
        if (lane == 0) { smax[0][h*4 + wid] = t0; smax[1][h*4 + wid] = t1; }
    }
    __syncthreads();

#pragma unroll
    for (int h = 0; h < HH; ++h) {
        const float m0 = fmaxf(fmaxf(smax[0][h*4+0], smax[0][h*4+1]),
                               fmaxf(smax[0][h*4+2], smax[0][h*4+3]));
        const float m1 = fmaxf(fmaxf(smax[1][h*4+0], smax[1][h*4+1]),
                               fmaxf(smax[1][h*4+2], smax[1][h*4+3]));
        l0[h].x = __expf(l0[h].x - m0); l0[h].y = __expf(l0[h].y - m0);
        l0[h].z = __expf(l0[h].z - m0); l0[h].w = __expf(l0[h].w - m0);
        l1[h].x = __expf(l1[h].x - m1); l1[h].y = __expf(l1[h].y - m1);
        l1[h].z = __expf(l1[h].z - m1); l1[h].w = __expf(l1[h].w - m1);
        float s0 = (l0[h].x + l0[h].y) + (l0[h].z + l0[h].w);
        float s1 = (l1[h].x + l1[h].y) + (l1[h].z + l1[h].w);
#pragma unroll
        for (int off = 32; off > 0; off >>= 1) {
            s0 += __shfl_xor(s0, off, 64);
            s1 += __shfl_xor(s1, off, 64);
        }
        if (lane == 0) { ssum[0][h*4 + wid] = s0; ssum[1][h*4 + wid] = s1; }
    }
    __syncthreads();

#pragma unroll
    for (int h = 0; h < HH; ++h) {
        const float i0 = 1.f / (ssum[0][h*4+0] + ssum[0][h*4+1] +
                                ssum[0][h*4+2] + ssum[0][h*4+3]);
        const float i1 = 1.f / (ssum[1][h*4+0] + ssum[1][h*4+1] +
                                ssum[1][h*4+2] + ssum[1][h*4+3]);
        l0[h].x *= i0; l0[h].y *= i0; l0[h].z *= i0; l0[h].w *= i0;
        l1[h].x *= i1; l1[h].y *= i1; l1[h].z *= i1; l1[h].w *= i1;
    }

    // ---- expand H -> HP, non-temporal float4 stores ----------------------
    fvec4* ab = ((fvec4*)aexp) + ((size_t)b*HPP*NN + n0) * 256;
#pragma unroll 4
    for (int o = 0; o < HPP; ++o) {
        fvec4 e0 = {0.f,0.f,0.f,0.f}, e1 = {0.f,0.f,0.f,0.f};
#pragma unroll
        for (int h = 0; h < HH; ++h) {
            const float w = wexp_s[o*HH + h];
            e0.x = fmaf(w, l0[h].x, e0.x); e0.y = fmaf(w, l0[h].y, e0.y);
            e0.z = fmaf(w, l0[h].z, e0.z); e0.w = fmaf(w, l0[h].w, e0.w);
            e1.x = fmaf(w, l1[h].x, e1.x); e1.y = fmaf(w, l1[h].y, e1.y);
            e1.z = fmaf(w, l1[h].z, e1.z); e1.w = fmaf(w, l1[h].w, e1.w);
        }
        fvec4* p0 = ab + (size_t)o * NN * 256 + m4;
        __builtin_nontemporal_store(e0, p0);        // row n0
        __builtin_nontemporal_store(e1, p0 + 256);  // row n0+1
    }
}

// ---------------------------------------------------------------------------
// Kernel 3: per (b,n): depthwise 3x3 conv (+bias,ReLU) over A_exp,
// HP->H reduce into REGISTER accumulators (float4 acc[12]), softmax in regs,
// probs -> LDS (aliased over the row staging buffers), then PV with float4
// v loads.  Double-buffered row staging, 1 barrier/channel.
// XCD pinning: batch from blockIdx bit2 so each XCD's L2 keeps one batch's V
// (3 MB) resident; adjacent n land on the same XCD for conv-halo row reuse.
// ---------------------------------------------------------------------------
#define ROWSTR 1040            // 4 front pad + 1024 data + tail pad (16B aligned)
#define BUFSTR (3*ROWSTR)      // 3 rows per buffer

__global__ __launch_bounds__(256, 3)
void conv_red_pv(const float* __restrict__ aexp, const float* __restrict__ Wloc,
                 const float* __restrict__ bloc, const float* __restrict__ Wred,
                 const float* __restrict__ vws, float* __restrict__ hout)
{
    __shared__ float smem[HH * NN];     // 48 KB: rows dbuf (2*3120) then attn2 probs
    __shared__ float wloc_s[HPP * 9];
    __shared__ float bloc_s[HPP];
    __shared__ float wred_s[HH * HPP];
    __shared__ float redbuf[HH * 4];

    const int tid  = threadIdx.x;
    const int lane = tid & 63, wid = tid >> 6;
    const int x    = blockIdx.x & 7;
    const int b    = x >> 2;
    const int n    = ((x & 3) << 8) | (blockIdx.x >> 3);

    for (int idx = tid; idx < HPP*9; idx += 256) wloc_s[idx] = Wloc[idx];
    if (tid < HPP) bloc_s[tid] = bloc[tid];
    for (int idx = tid; idx < HH*HPP; idx += 256) wred_s[idx] = Wred[idx] * SCALE;
    // explicit halo zero: 2 buffers x 3 rows x 2 cells = 12 cells
    if (tid < 12) {
        const int bu = tid / 6, rr = (tid % 6) / 2, cell = tid & 1;
        smem[bu*BUFSTR + rr*ROWSTR + (cell ? 1028 : 3)] = 0.f;
    }

    // row validity (conv SAME padding at n edges)
    const bool rv[3] = { n > 0, true, n < NN-1 };

    // ---- prefetch channel 0 ----------------------------------------------
    float4 ld[3];
#pragma unroll
    for (int r = 0; r < 3; ++r) {
        if (rv[r]) {
            const size_t row = ((size_t)(b*HPP + 0)*NN + (n-1+r));
            ld[r] = ((const float4*)aexp)[row*256 + tid];
        } else ld[r] = make_float4(0.f,0.f,0.f,0.f);
    }
#pragma unroll
    for (int r = 0; r < 3; ++r)
        *((float4*)(smem + 0*BUFSTR + r*ROWSTR + 4) + tid) = ld[r];

    float4 acc[HH];
#pragma unroll
    for (int i = 0; i < HH; ++i) acc[i] = make_float4(0.f,0.f,0.f,0.f);

    // ---- conv + reduce loop ----------------------------------------------
    for (int o = 0; o < HPP; ++o) {
        const int buf = o & 1;
        if (o < HPP-1) {
#pragma unroll
            for (int r = 0; r < 3; ++r) {
                if (rv[r]) {
                    const size_t row = ((size_t)(b*HPP + (o+1))*NN + (n-1+r));
                    ld[r] = ((const float4*)aexp)[row*256 + tid];
                } else ld[r] = make_float4(0.f,0.f,0.f,0.f);
            }
        }
        __syncthreads();   // staging of channel o visible to all

        const float* w  = wloc_s + o*9;
        const float  bb = bloc_s[o];
        const float* r0 = smem + buf*BUFSTR + 0*ROWSTR + 3 + 4*tid;
        const float* r1 = smem + buf*BUFSTR + 1*ROWSTR + 3 + 4*tid;
        const float* r2 = smem + buf*BUFSTR + 2*ROWSTR + 3 + 4*tid;

        float val[4];
#pragma unroll
        for (int j = 0; j < 4; ++j) {
            float a = bb;
            a = fmaf(r0[j+0], w[0], a); a = fmaf(r0[j+1], w[1], a); a = fmaf(r0[j+2], w[2], a);
            a = fmaf(r1[j+0], w[3], a); a = fmaf(r1[j+1], w[4], a); a = fmaf(r1[j+2], w[5], a);
            a = fmaf(r2[j+0], w[6], a); a = fmaf(r2[j+1], w[7], a); a = fmaf(r2[j+2], w[8], a);
            val[j] = fmaxf(a, 0.f);
        }
#pragma unroll
        for (int i = 0; i < HH; ++i) {
            const float wr = wred_s[i*HPP + o];
            acc[i].x = fmaf(wr, val[0], acc[i].x);
            acc[i].y = fmaf(wr, val[1], acc[i].y);
            acc[i].z = fmaf(wr, val[2], acc[i].z);
            acc[i].w = fmaf(wr, val[3], acc[i].w);
        }
        if (o < HPP-1) {
#pragma unroll
            for (int r = 0; r < 3; ++r)
                *((float4*)(smem + (buf^1)*BUFSTR + r*ROWSTR + 4) + tid) = ld[r];
        }
    }

    // ---- softmax over m (register rows, shfl + LDS cross-wave) -----------
#pragma unroll
    for (int i = 0; i < HH; ++i) {
        float t = fmaxf(fmaxf(acc[i].x, acc[i].y), fmaxf(acc[i].z, acc[i].w));
#pragma unroll
        for (int off = 32; off > 0; off >>= 1) t = fmaxf(t, __shfl_xor(t, off, 64));
        if (lane == 0) redbuf[i*4 + wid] = t;
    }
    __syncthreads();   // also separates last conv LDS reads from prob writes
    float mh[HH];
#pragma unroll
    for (int i = 0; i < HH; ++i)
        mh[i] = fmaxf(fmaxf(redbuf[i*4+0], redbuf[i*4+1]),
                      fmaxf(redbuf[i*4+2], redbuf[i*4+3]));
    __syncthreads();

#pragma unroll
    for (int i = 0; i < HH; ++i) {
        acc[i].x = __expf(acc[i].x - mh[i]);
        acc[i].y = __expf(acc[i].y - mh[i]);
        acc[i].z = __expf(acc[i].z - mh[i]);
        acc[i].w = __expf(acc[i].w - mh[i]);
        float s = (acc[i].x + acc[i].y) + (acc[i].z + acc[i].w);
#pragma unroll
        for (int off = 32; off > 0; off >>= 1) s += __shfl_xor(s, off, 64);
        if (lane == 0) redbuf[i*4 + wid] = s;
    }
    __syncthreads();
#pragma unroll
    for (int i = 0; i < HH; ++i) {
        const float inv = 1.f / (redbuf[i*4+0] + redbuf[i*4+1] +
                                 redbuf[i*4+2] + redbuf[i*4+3]);
        acc[i].x *= inv; acc[i].y *= inv; acc[i].z *= inv; acc[i].w *= inv;
        ((float4*)smem)[i*256 + tid] = acc[i];   // probs into LDS (alias rows)
    }
    __syncthreads();

    // ---- PV: wave owns 3 heads; lanes = (mg,dq); float4 v loads ----------
    const int mg = lane >> 4, dq = lane & 15;
    const size_t outbase = ((size_t)(b*NN + n)) * CC;
#pragma unroll
    for (int t = 0; t < 3; ++t) {
        const int i = wid*3 + t;
        const float4* vp = (const float4*)(vws + (((size_t)b*HH + i)*NN)*HD) + dq;
        const float*  pr = smem + i*NN + mg;
        float4 a4 = make_float4(0.f,0.f,0.f,0.f);
#pragma unroll 8
        for (int m0 = 0; m0 < NN; m0 += 4) {
            const float  p  = pr[m0];
            const float4 vv = vp[(size_t)(m0+mg)*16];
            a4.x = fmaf(p, vv.x, a4.x);
            a4.y = fmaf(p, vv.y, a4.y);
            a4.z = fmaf(p, vv.z, a4.z);
            a4.w = fmaf(p, vv.w, a4.w);
        }
        a4.x += __shfl_xor(a4.x, 16, 64); a4.x += __shfl_xor(a4.x, 32, 64);
        a4.y += __shfl_xor(a4.y, 16, 64); a4.y += __shfl_xor(a4.y, 32, 64);
        a4.z += __shfl_xor(a4.z, 16, 64); a4.z += __shfl_xor(a4.z, 32, 64);
        a4.w += __shfl_xor(a4.w, 16, 64); a4.w += __shfl_xor(a4.w, 32, 64);
        if (mg == 0)
            ((float4*)(hout + outbase + i*HD))[dq] = a4;
    }
}

// ---------------------------------------------------------------------------
// Kernel 4: final projection  out = head_out @ Wproj^T + bias
// ---------------------------------------------------------------------------
__global__ __launch_bounds__(256)
void proj_gemm(const float* __restrict__ A, const float* __restrict__ Wp,
               const float* __restrict__ bias, float* __restrict__ out)
{
    __shared__ float As[16][68];
    __shared__ float Bs[16][68];

    const int tid  = threadIdx.x;
    const int bn   = blockIdx.x;   // 0..11
    const int bm   = blockIdx.y;   // 0..31
    const int tx   = tid & 15, ty = tid >> 4;
    const int lrow = tid >> 2;
    const int lk   = (tid & 3) << 2;

    const float* Asrc = A  + (size_t)(bm*64 + lrow) * 768;
    const float* Bsrc = Wp + (size_t)(bn*64 + lrow) * 768;

    float c[4][4] = {};

    for (int k0 = 0; k0 < 768; k0 += 16) {
        float4 av = *(const float4*)(Asrc + k0 + lk);
        float4 bv = *(const float4*)(Bsrc + k0 + lk);
        __syncthreads();
        As[lk+0][lrow] = av.x; As[lk+1][lrow] = av.y;
        As[lk+2][lrow] = av.z; As[lk+3][lrow] = av.w;
        Bs[lk+0][lrow] = bv.x; Bs[lk+1][lrow] = bv.y;
        Bs[lk+2][lrow] = bv.z; Bs[lk+3][lrow] = bv.w;
        __syncthreads();
#pragma unroll
        for (int kk = 0; kk < 16; ++kk) {
            float a[4], b[4];
#pragma unroll
            for (int i = 0; i < 4; ++i) a[i] = As[kk][ty*4 + i];
#pragma unroll
            for (int j = 0; j < 4; ++j) b[j] = Bs[kk][tx*4 + j];
#pragma unroll
            for (int i = 0; i < 4; ++i)
#pragma unroll
                for (int j = 0; j < 4; ++j)
                    c[i][j] = fmaf(a[i], b[j], c[i][j]);
        }
    }

#pragma unroll
    for (int i = 0; i < 4; ++i) {
        const int t = bm*64 + ty*4 + i;
#pragma unroll
        for (int j = 0; j < 4; ++j) {
            const int col = bn*64 + tx*4 + j;
            out[(size_t)t*768 + col] = c[i][j] + bias[col];
        }
    }
}

// ---------------------------------------------------------------------------
extern "C" void kernel_launch(void* const* d_in, const int* in_sizes, int n_in,
                              void* d_out, int out_size, void* d_ws, size_t ws_size,
                              hipStream_t stream)
{
    const float* x     = (const float*)d_in[0];
    const float* Wqk   = (const float*)d_in[1];
    const float* Wv    = (const float*)d_in[2];
    const float* Wexp  = (const float*)d_in[3];
    const float* Wloc  = (const float*)d_in[4];
    const float* bloc  = (const float*)d_in[5];
    const float* Wred  = (const float*)d_in[6];
    const float* Wproj = (const float*)d_in[7];
    const float* bproj = (const float*)d_in[8];

    float* out  = (float*)d_out;              // (B,N,C) = 1,572,864 floats
    float* aexp = out + (size_t)SEG;          // (B,HP,N,N) = 50,331,648 floats
    float* ws   = (float*)d_ws;               // q_tok, k_t, v, head_out = 25.2 MB

    qkv_gemm   <<<dim3(36, 32), 256, 0, stream>>>(x, Wqk, Wv, ws);
    attn_expand<<<dim3(BB * NN / 2), 256, 0, stream>>>(ws + QOFF, ws + KOFF, Wexp, aexp);
    conv_red_pv<<<dim3(BB * NN), 256, 0, stream>>>(aexp, Wloc, bloc, Wred,
                                                   ws + VOFF, ws + HOFF);
    proj_gemm  <<<dim3(12, 32), 256, 0, stream>>>(ws + HOFF, Wproj, bproj, out);
}

// Round 2
// 768.941 us; speedup vs baseline: 1.3549x; 1.0615x over previous
//
#include <hip/hip_runtime.h>
#include <math.h>

// Problem constants
#define BB    2
#define NN    1024
#define CC    768
#define HH    12
#define HPP   24
#define HD    64
#define SCALE 0.125f

typedef float fvec4 __attribute__((ext_vector_type(4)));

// workspace layout (floats)
#define SEG   (2*1024*768)   // 1,572,864 floats per tensor
#define QOFF  0              // q_tok: (B*N, 768) token-major
#define KOFF  (SEG)          // k_t:   (B, 768, N) transposed
#define VOFF  (2*SEG)        // v:     (B, H, N, HD)
#define HOFF  (3*SEG)        // head_out: (B, N, C)

// ---------------------------------------------------------------------------
// Kernel 1: fused QKV projection.  x(2048,768) @ [Wqk;Wv]^T.
// ---------------------------------------------------------------------------
__global__ __launch_bounds__(256)
void qkv_gemm(const float* __restrict__ x, const float* __restrict__ Wqk,
              const float* __restrict__ Wv, float* __restrict__ ws)
{
    __shared__ float As[16][68];
    __shared__ float Bs[16][68];
    float* qtok = ws + QOFF;
    float* kt   = ws + KOFF;
    float* vws  = ws + VOFF;

    const int tid  = threadIdx.x;
    const int bn   = blockIdx.x;        // 0..35
    const int bm   = blockIdx.y;        // 0..31
    const int tx   = tid & 15, ty = tid >> 4;
    const int lrow = tid >> 2;
    const int lk   = (tid & 3) << 2;

    const int jrow = bn * 64 + lrow;
    const float* Bsrc = (jrow < 1536) ? (Wqk + (size_t)jrow * 768)
                                      : (Wv  + (size_t)(jrow - 1536) * 768);
    const float* Asrc = x + (size_t)(bm * 64 + lrow) * 768;

    float c[4][4] = {};

    for (int k0 = 0; k0 < 768; k0 += 16) {
        float4 av = *(const float4*)(Asrc + k0 + lk);
        float4 bv = *(const float4*)(Bsrc + k0 + lk);
        __syncthreads();
        As[lk+0][lrow] = av.x; As[lk+1][lrow] = av.y;
        As[lk+2][lrow] = av.z; As[lk+3][lrow] = av.w;
        Bs[lk+0][lrow] = bv.x; Bs[lk+1][lrow] = bv.y;
        Bs[lk+2][lrow] = bv.z; Bs[lk+3][lrow] = bv.w;
        __syncthreads();
#pragma unroll
        for (int kk = 0; kk < 16; ++kk) {
            float a[4], b[4];
#pragma unroll
            for (int i = 0; i < 4; ++i) a[i] = As[kk][ty*4 + i];
#pragma unroll
            for (int j = 0; j < 4; ++j) b[j] = Bs[kk][tx*4 + j];
#pragma unroll
            for (int i = 0; i < 4; ++i)
#pragma unroll
                for (int j = 0; j < 4; ++j)
                    c[i][j] = fmaf(a[i], b[j], c[i][j]);
        }
    }

#pragma unroll
    for (int i = 0; i < 4; ++i) {
        const int t = bm*64 + ty*4 + i;
        const int b = t >> 10, n = t & 1023;
#pragma unroll
        for (int j = 0; j < 4; ++j) {
            const int col = bn*64 + tx*4 + j;
            const float val = c[i][j];
            if (col < 768) {
                qtok[(size_t)t*768 + col] = val;
            } else if (col < 1536) {
                const int p = col - 768;
                kt[((size_t)(b*768 + p))*NN + n] = val;
            } else {
                const int p = col - 1536;
                vws[(((size_t)b*HH + (p >> 6))*NN + n)*HD + (p & 63)] = val;
            }
        }
    }
}

// ---------------------------------------------------------------------------
// Kernel 2: per block = 2 consecutive tokens; one K float4 load feeds both
// tokens' logits.  XCD pinning keeps one batch's K per XCD L2.
// ---------------------------------------------------------------------------
__global__ __launch_bounds__(256, 4)
void attn_expand(const float* __restrict__ qtok, const float* __restrict__ kt,
                 const float* __restrict__ Wexp, float* __restrict__ aexp)
{
    __shared__ __align__(16) float qs[2*CC];
    __shared__ float wexp_s[HPP * HH];
    __shared__ float smax[2][HH * 4];
    __shared__ float ssum[2][HH * 4];

    const int tid  = threadIdx.x;
    const int lane = tid & 63, wid = tid >> 6;
    const int x    = blockIdx.x & 7;
    const int b    = x >> 2;
    const int np   = ((x & 3) << 7) | (blockIdx.x >> 3);
    const int n0   = np << 1;
    const int m4   = tid;

    const fvec4* qsrc = (const fvec4*)(qtok + (size_t)(b*NN + n0) * CC);
    ((fvec4*)qs)[tid] = qsrc[tid];
    if (tid < 128) ((fvec4*)qs)[256 + tid] = qsrc[256 + tid];
    for (int i2 = tid; i2 < HPP*HH; i2 += 256) wexp_s[i2] = Wexp[i2];
    __syncthreads();

    fvec4 l0[HH], l1[HH];
#pragma unroll
    for (int h = 0; h < HH; ++h) {
        fvec4 a0 = {0.f,0.f,0.f,0.f}, a1 = {0.f,0.f,0.f,0.f};
        const fvec4* kr = ((const fvec4*)kt) + (size_t)(b*768 + h*64) * 256 + m4;
        const float* q0p = qs + h*64;
        const float* q1p = qs + CC + h*64;
#pragma unroll 8
        for (int d = 0; d < 64; ++d) {
            const fvec4 kv = kr[(size_t)d * 256];
            const float qa = q0p[d];
            const float qb = q1p[d];
            a0.x = fmaf(kv.x, qa, a0.x); a0.y = fmaf(kv.y, qa, a0.y);
            a0.z = fmaf(kv.z, qa, a0.z); a0.w = fmaf(kv.w, qa, a0.w);
            a1.x = fmaf(kv.x, qb, a1.x); a1.y = fmaf(kv.y, qb, a1.y);
            a1.z = fmaf(kv.z, qb, a1.z); a1.w = fmaf(kv.w, qb, a1.w);
        }
        l0[h].x = a0.x*SCALE; l0[h].y = a0.y*SCALE;
        l0[h].z = a0.z*SCALE; l0[h].w = a0.w*SCALE;
        l1[h].x = a1.x*SCALE; l1[h].y = a1.y*SCALE;
        l1[h].z = a1.z*SCALE; l1[h].w = a1.w*SCALE;
    }

#pragma unroll
    for (int h = 0; h < HH; ++h) {
        float t0 = fmaxf(fmaxf(l0[h].x, l0[h].y), fmaxf(l0[h].z, l0[h].w));
        float t1 = fmaxf(fmaxf(l1[h].x, l1[h].y), fmaxf(l1[h].z, l1[h].w));
#pragma unroll
        for (int off = 32; off > 0; off >>= 1) {
            t0 = fmaxf(t0, __shfl_xor(t0, off, 64));
            t1 = fmaxf(t1, __shfl_xor(t1, off, 64));
        }
        if (lane == 0) { smax[0][h*4 + wid] = t0; smax[1][h*4 + wid] = t1; }
    }
    __syncthreads();

#pragma unroll
    for (int h = 0; h < HH; ++h) {
        const float m0 = fmaxf(fmaxf(smax[0][h*4+0], smax[0][h*4+1]),
                               fmaxf(smax[0][h*4+2], smax[0][h*4+3]));
        const float m1 = fmaxf(fmaxf(smax[1][h*4+0], smax[1][h*4+1]),
                               fmaxf(smax[1][h*4+2], smax[1][h*4+3]));
        l0[h].x = __expf(l0[h].x - m0); l0[h].y = __expf(l0[h].y - m0);
        l0[h].z = __expf(l0[h].z - m0); l0[h].w = __expf(l0[h].w - m0);
        l1[h].x = __expf(l1[h].x - m1); l1[h].y = __expf(l1[h].y - m1);
        l1[h].z = __expf(l1[h].z - m1); l1[h].w = __expf(l1[h].w - m1);
        float s0 = (l0[h].x + l0[h].y) + (l0[h].z + l0[h].w);
        float s1 = (l1[h].x + l1[h].y) + (l1[h].z + l1[h].w);
#pragma unroll
        for (int off = 32; off > 0; off >>= 1) {
            s0 += __shfl_xor(s0, off, 64);
            s1 += __shfl_xor(s1, off, 64);
        }
        if (lane == 0) { ssum[0][h*4 + wid] = s0; ssum[1][h*4 + wid] = s1; }
    }
    __syncthreads();

#pragma unroll
    for (int h = 0; h < HH; ++h) {
        const float i0 = 1.f / (ssum[0][h*4+0] + ssum[0][h*4+1] +
                                ssum[0][h*4+2] + ssum[0][h*4+3]);
        const float i1 = 1.f / (ssum[1][h*4+0] + ssum[1][h*4+1] +
                                ssum[1][h*4+2] + ssum[1][h*4+3]);
        l0[h].x *= i0; l0[h].y *= i0; l0[h].z *= i0; l0[h].w *= i0;
        l1[h].x *= i1; l1[h].y *= i1; l1[h].z *= i1; l1[h].w *= i1;
    }

    fvec4* ab = ((fvec4*)aexp) + ((size_t)b*HPP*NN + n0) * 256;
#pragma unroll 4
    for (int o = 0; o < HPP; ++o) {
        fvec4 e0 = {0.f,0.f,0.f,0.f}, e1 = {0.f,0.f,0.f,0.f};
#pragma unroll
        for (int h = 0; h < HH; ++h) {
            const float w = wexp_s[o*HH + h];
            e0.x = fmaf(w, l0[h].x, e0.x); e0.y = fmaf(w, l0[h].y, e0.y);
            e0.z = fmaf(w, l0[h].z, e0.z); e0.w = fmaf(w, l0[h].w, e0.w);
            e1.x = fmaf(w, l1[h].x, e1.x); e1.y = fmaf(w, l1[h].y, e1.y);
            e1.z = fmaf(w, l1[h].z, e1.z); e1.w = fmaf(w, l1[h].w, e1.w);
        }
        fvec4* p0 = ab + (size_t)o * NN * 256 + m4;
        __builtin_nontemporal_store(e0, p0);
        __builtin_nontemporal_store(e1, p0 + 256);
    }
}

// ---------------------------------------------------------------------------
// Kernel 3 (v3): 512 threads, 2 tokens per block (half-block per token).
// Conv is REGISTER-RESIDENT: thread holds its aligned float4 row window from
// global; column taps via __shfl_up/down; wave-edge halo = 2 conditional
// scalar global loads.  No LDS staging, NO barriers in the channel loop,
// zero bank conflicts.  Weights read via uniform (scalar) global loads.
// PV: unit = (head, d-half); each V float4 load feeds BOTH tokens (V traffic
// halved).  Probs staged in a 32 KB LDS buffer, 3 batches of 4 heads.
// ---------------------------------------------------------------------------
__global__ __launch_bounds__(512, 4)
void conv_red_pv(const float* __restrict__ aexp, const float* __restrict__ Wloc,
                 const float* __restrict__ bloc, const float* __restrict__ Wred,
                 const float* __restrict__ vws, float* __restrict__ hout)
{
    __shared__ __align__(16) float probs[8][NN];   // 32 KB (4 heads x 2 tokens)
    __shared__ float redbuf[2][HH][4];

    const int tid  = threadIdx.x;
    const int lane = tid & 63;
    const int w    = tid >> 6;          // wave 0..7
    const int tk   = w >> 2;            // token within pair
    const int wq   = w & 3;             // m-chunk within half-block
    const int t    = tid & 255;         // m float4 index 0..255

    const int x  = blockIdx.x & 7;      // XCD slot
    const int b  = x >> 2;
    const int np = ((x & 3) << 7) | (blockIdx.x >> 3);
    const int n0 = np << 1;
    const int n  = n0 + tk;             // this half-block's token

    const bool rv0 = n > 0, rv2 = n < NN - 1;

    float4 acc[HH];
#pragma unroll
    for (int i = 0; i < HH; ++i) acc[i] = make_float4(0.f,0.f,0.f,0.f);

    // --- channel-row loader (3 rows n-1..n+1 of channel o, + wave halos) ---
    auto loadch = [&](int o, float4 ld[3], float hl[3], float hr[3]) {
        const float* cb = aexp + ((size_t)(b*HPP + o) * NN + (size_t)(n-1)) * NN;
#pragma unroll
        for (int r = 0; r < 3; ++r) {
            const bool ok = (r == 0) ? rv0 : (r == 2 ? rv2 : true);
            const float* rp = cb + (size_t)r * NN;
            if (ok) {
                ld[r] = ((const float4*)rp)[t];
                hl[r] = (lane == 0  && wq > 0) ? rp[4*t - 1] : 0.f;
                hr[r] = (lane == 63 && wq < 3) ? rp[4*t + 4] : 0.f;
            } else {
                ld[r] = make_float4(0.f,0.f,0.f,0.f);
                hl[r] = 0.f; hr[r] = 0.f;
            }
        }
    };

    float4 ld[3]; float hl[3], hr[3];
    loadch(0, ld, hl, hr);

    // --- conv + HP->H reduce, no barriers --------------------------------
    for (int o = 0; o < HPP; ++o) {
        float4 l2[3]; float h2l[3], h2r[3];
        if (o < HPP-1) loadch(o+1, l2, h2l, h2r);

        const float* wl = Wloc + o*9;            // uniform -> s_load
        const float  bb = bloc[o];
        float v0 = bb, v1 = bb, v2 = bb, v3 = bb;
#pragma unroll
        for (int r = 0; r < 3; ++r) {
            const float w0 = wl[r*3+0], w1 = wl[r*3+1], w2 = wl[r*3+2];
            const float4 c = ld[r];
            float lf = __shfl_up(c.w, 1, 64);
            float rt = __shfl_down(c.x, 1, 64);
            if (lane == 0)  lf = hl[r];
            if (lane == 63) rt = hr[r];
            v0 = fmaf(w0, lf,  v0); v0 = fmaf(w1, c.x, v0); v0 = fmaf(w2, c.y, v0);
            v1 = fmaf(w0, c.x, v1); v1 = fmaf(w1, c.y, v1); v1 = fmaf(w2, c.z, v1);
            v2 = fmaf(w0, c.y, v2); v2 = fmaf(w1, c.z, v2); v2 = fmaf(w2, c.w, v2);
            v3 = fmaf(w0, c.z, v3); v3 = fmaf(w1, c.w, v3); v3 = fmaf(w2, rt,  v3);
        }
        v0 = fmaxf(v0, 0.f); v1 = fmaxf(v1, 0.f);
        v2 = fmaxf(v2, 0.f); v3 = fmaxf(v3, 0.f);
#pragma unroll
        for (int i = 0; i < HH; ++i) {
            const float wr = Wred[i*HPP + o];    // uniform -> s_load
            acc[i].x = fmaf(wr, v0, acc[i].x);
            acc[i].y = fmaf(wr, v1, acc[i].y);
            acc[i].z = fmaf(wr, v2, acc[i].z);
            acc[i].w = fmaf(wr, v3, acc[i].w);
        }
        if (o < HPP-1) {
#pragma unroll
            for (int r = 0; r < 3; ++r) { ld[r]=l2[r]; hl[r]=h2l[r]; hr[r]=h2r[r]; }
        }
    }
#pragma unroll
    for (int i = 0; i < HH; ++i) {
        acc[i].x *= SCALE; acc[i].y *= SCALE;
        acc[i].z *= SCALE; acc[i].w *= SCALE;
    }

    // --- softmax over m per (token, head) --------------------------------
#pragma unroll
    for (int i = 0; i < HH; ++i) {
        float tm = fmaxf(fmaxf(acc[i].x, acc[i].y), fmaxf(acc[i].z, acc[i].w));
#pragma unroll
        for (int off = 32; off > 0; off >>= 1) tm = fmaxf(tm, __shfl_xor(tm, off, 64));
        if (lane == 0) redbuf[tk][i][wq] = tm;
    }
    __syncthreads();
    float mh[HH];
#pragma unroll
    for (int i = 0; i < HH; ++i)
        mh[i] = fmaxf(fmaxf(redbuf[tk][i][0], redbuf[tk][i][1]),
                      fmaxf(redbuf[tk][i][2], redbuf[tk][i][3]));
    __syncthreads();

#pragma unroll
    for (int i = 0; i < HH; ++i) {
        acc[i].x = __expf(acc[i].x - mh[i]);
        acc[i].y = __expf(acc[i].y - mh[i]);
        acc[i].z = __expf(acc[i].z - mh[i]);
        acc[i].w = __expf(acc[i].w - mh[i]);
        float s = (acc[i].x + acc[i].y) + (acc[i].z + acc[i].w);
#pragma unroll
        for (int off = 32; off > 0; off >>= 1) s += __shfl_xor(s, off, 64);
        if (lane == 0) redbuf[tk][i][wq] = s;
    }
    __syncthreads();
#pragma unroll
    for (int i = 0; i < HH; ++i) {
        const float inv = 1.f / (redbuf[tk][i][0] + redbuf[tk][i][1] +
                                 redbuf[tk][i][2] + redbuf[tk][i][3]);
        acc[i].x *= inv; acc[i].y *= inv; acc[i].z *= inv; acc[i].w *= inv;
    }

    // --- PV: 3 batches of 4 heads; wave = (head-in-batch, d-half) unit ----
    const int hq = w >> 1;              // head offset in batch: 0..3
    const int dh = w & 1;               // d-half 0/1
    const int mg = lane >> 3;           // m-group 0..7
    const int dq = lane & 7;            // f4 within half

    for (int g = 0; g < 3; ++g) {
        __syncthreads();                // prior batch's PV reads done
#pragma unroll
        for (int q2 = 0; q2 < 4; ++q2)
            ((float4*)&probs[q2*2 + tk][0])[t] = acc[4*g + q2];
        __syncthreads();

        const int h = 4*g + hq;
        const float4* vp = ((const float4*)vws)
                         + ((size_t)(b*HH + h) * NN) * 16 + dh*8 + dq;
        const float* p0 = &probs[hq*2 + 0][0] + mg;
        const float* p1 = &probs[hq*2 + 1][0] + mg;
        float4 a0 = make_float4(0.f,0.f,0.f,0.f);
        float4 a1 = make_float4(0.f,0.f,0.f,0.f);
#pragma unroll 8
        for (int m0 = 0; m0 < NN; m0 += 8) {
            const float  pa = p0[m0];
            const float  pb = p1[m0];
            const float4 vv = vp[(size_t)(m0 + mg) * 16];
            a0.x = fmaf(pa, vv.x, a0.x); a0.y = fmaf(pa, vv.y, a0.y);
            a0.z = fmaf(pa, vv.z, a0.z); a0.w = fmaf(pa, vv.w, a0.w);
            a1.x = fmaf(pb, vv.x, a1.x); a1.y = fmaf(pb, vv.y, a1.y);
            a1.z = fmaf(pb, vv.z, a1.z); a1.w = fmaf(pb, vv.w, a1.w);
        }
#pragma unroll
        for (int off = 8; off < 64; off <<= 1) {
            a0.x += __shfl_xor(a0.x, off, 64); a0.y += __shfl_xor(a0.y, off, 64);
            a0.z += __shfl_xor(a0.z, off, 64); a0.w += __shfl_xor(a0.w, off, 64);
            a1.x += __shfl_xor(a1.x, off, 64); a1.y += __shfl_xor(a1.y, off, 64);
            a1.z += __shfl_xor(a1.z, off, 64); a1.w += __shfl_xor(a1.w, off, 64);
        }
        if (mg == 0) {
            ((float4*)(hout + ((size_t)(b*NN + n0    ) * CC) + h*HD))[dh*8 + dq] = a0;
            ((float4*)(hout + ((size_t)(b*NN + n0 + 1) * CC) + h*HD))[dh*8 + dq] = a1;
        }
    }
}

// ---------------------------------------------------------------------------
// Kernel 4: final projection  out = head_out @ Wproj^T + bias
// ---------------------------------------------------------------------------
__global__ __launch_bounds__(256)
void proj_gemm(const float* __restrict__ A, const float* __restrict__ Wp,
               const float* __restrict__ bias, float* __restrict__ out)
{
    __shared__ float As[16][68];
    __shared__ float Bs[16][68];

    const int tid  = threadIdx.x;
    const int bn   = blockIdx.x;
    const int bm   = blockIdx.y;
    const int tx   = tid & 15, ty = tid >> 4;
    const int lrow = tid >> 2;
    const int lk   = (tid & 3) << 2;

    const float* Asrc = A  + (size_t)(bm*64 + lrow) * 768;
    const float* Bsrc = Wp + (size_t)(bn*64 + lrow) * 768;

    float c[4][4] = {};

    for (int k0 = 0; k0 < 768; k0 += 16) {
        float4 av = *(const float4*)(Asrc + k0 + lk);
        float4 bv = *(const float4*)(Bsrc + k0 + lk);
        __syncthreads();
        As[lk+0][lrow] = av.x; As[lk+1][lrow] = av.y;
        As[lk+2][lrow] = av.z; As[lk+3][lrow] = av.w;
        Bs[lk+0][lrow] = bv.x; Bs[lk+1][lrow] = bv.y;
        Bs[lk+2][lrow] = bv.z; Bs[lk+3][lrow] = bv.w;
        __syncthreads();
#pragma unroll
        for (int kk = 0; kk < 16; ++kk) {
            float a[4], b[4];
#pragma unroll
            for (int i = 0; i < 4; ++i) a[i] = As[kk][ty*4 + i];
#pragma unroll
            for (int j = 0; j < 4; ++j) b[j] = Bs[kk][tx*4 + j];
#pragma unroll
            for (int i = 0; i < 4; ++i)
#pragma unroll
                for (int j = 0; j < 4; ++j)
                    c[i][j] = fmaf(a[i], b[j], c[i][j]);
        }
    }

#pragma unroll
    for (int i = 0; i < 4; ++i) {
        const int t = bm*64 + ty*4 + i;
#pragma unroll
        for (int j = 0; j < 4; ++j) {
            const int col = bn*64 + tx*4 + j;
            out[(size_t)t*768 + col] = c[i][j] + bias[col];
        }
    }
}

// ---------------------------------------------------------------------------
extern "C" void kernel_launch(void* const* d_in, const int* in_sizes, int n_in,
                              void* d_out, int out_size, void* d_ws, size_t ws_size,
                              hipStream_t stream)
{
    const float* x     = (const float*)d_in[0];
    const float* Wqk   = (const float*)d_in[1];
    const float* Wv    = (const float*)d_in[2];
    const float* Wexp  = (const float*)d_in[3];
    const float* Wloc  = (const float*)d_in[4];
    const float* bloc  = (const float*)d_in[5];
    const float* Wred  = (const float*)d_in[6];
    const float* Wproj = (const float*)d_in[7];
    const float* bproj = (const float*)d_in[8];

    float* out  = (float*)d_out;              // (B,N,C)
    float* aexp = out + (size_t)SEG;          // (B,HP,N,N)
    float* ws   = (float*)d_ws;

    qkv_gemm   <<<dim3(36, 32), 256, 0, stream>>>(x, Wqk, Wv, ws);
    attn_expand<<<dim3(BB * NN / 2), 256, 0, stream>>>(ws + QOFF, ws + KOFF, Wexp, aexp);
    conv_red_pv<<<dim3(BB * NN / 2), 512, 0, stream>>>(aexp, Wloc, bloc, Wred,
                                                       ws + VOFF, ws + HOFF);
    proj_gemm  <<<dim3(12, 32), 256, 0, stream>>>(ws + HOFF, Wproj, bproj, out);
}

// Round 3
// 757.047 us; speedup vs baseline: 1.3761x; 1.0157x over previous
//
#include <hip/hip_runtime.h>
#include <math.h>

// Problem constants
#define BB    2
#define NN    1024
#define CC    768
#define HH    12
#define HPP   24
#define HD    64
#define SCALE 0.125f

typedef float fvec4 __attribute__((ext_vector_type(4)));

// workspace layout (floats)
#define SEG   (2*1024*768)   // 1,572,864 floats per tensor
#define QOFF  0              // q_tok: (B*N, 768) token-major
#define KOFF  (SEG)          // k_t:   (B, 768, N) transposed
#define VOFF  (2*SEG)        // v:     (B, H, N, HD)
#define HOFF  (3*SEG)        // head_out: (B, N, C)

// LDS strides for the 128x64 GEMM tiles
#define ASTR 132             // 128 + 4 pad
#define BSTR 68              // 64 + 4 pad

// ---------------------------------------------------------------------------
// Kernel 1: fused QKV projection.  x(2048,768) @ [Wqk;Wv]^T.
// 128x64 tile, 8x4 per thread, double-buffered LDS, 1 barrier / 16-K step.
// Epilogue scatters: q -> token-major, k -> (b,p,n) transposed, v -> (b,h,n,d).
// Each 64-col tile lies entirely in one of {q,k,v} (64 | 768), so the
// scatter branch is block-uniform.
// ---------------------------------------------------------------------------
__global__ __launch_bounds__(256)
void qkv_gemm(const float* __restrict__ x, const float* __restrict__ Wqk,
              const float* __restrict__ Wv, float* __restrict__ ws)
{
    __shared__ float As[2][16*ASTR];   // 16.9 KB
    __shared__ float Bs[2][16*BSTR];   //  8.7 KB
    float* qtok = ws + QOFF;
    float* kt   = ws + KOFF;
    float* vws  = ws + VOFF;

    const int tid = threadIdx.x;
    const int bn  = blockIdx.x;            // 0..35 (2304/64)
    const int bm  = blockIdx.y;            // 0..15 (2048/128)
    const int tx  = tid & 15, ty = tid >> 4;

    const int am  = tid >> 1, ak = (tid & 1) * 8;     // A stage: 2 float4 / thread
    const int bnr = tid >> 2, bk = (tid & 3) * 4;     // B stage: 1 float4 / thread

    const float* Ap = x + (size_t)(bm*128 + am) * 768 + ak;
    const int jrow  = bn*64 + bnr;
    const float* Bp = (jrow < 1536) ? (Wqk + (size_t)jrow * 768 + bk)
                                    : (Wv  + (size_t)(jrow - 1536) * 768 + bk);

    float acc[8][4] = {};

    // prologue: stage k-tile 0
    float4 a0 = *(const float4*)(Ap);
    float4 a1 = *(const float4*)(Ap + 4);
    float4 bv = *(const float4*)(Bp);
#pragma unroll
    for (int j = 0; j < 4; ++j) {
        As[0][(ak+j)*ASTR + am]   = ((const float*)&a0)[j];
        As[0][(ak+4+j)*ASTR + am] = ((const float*)&a1)[j];
        Bs[0][(bk+j)*BSTR + bnr]  = ((const float*)&bv)[j];
    }
    __syncthreads();

    for (int t = 0; t < 48; ++t) {
        const int cur = t & 1;
        if (t < 47) {
            a0 = *(const float4*)(Ap + (t+1)*16);
            a1 = *(const float4*)(Ap + (t+1)*16 + 4);
            bv = *(const float4*)(Bp + (t+1)*16);
        }
        const float* Asb = As[cur];
        const float* Bsb = Bs[cur];
#pragma unroll
        for (int kk = 0; kk < 16; ++kk) {
            float a[8], b[4];
#pragma unroll
            for (int i = 0; i < 8; ++i) a[i] = Asb[kk*ASTR + ty*8 + i];
#pragma unroll
            for (int j = 0; j < 4; ++j) b[j] = Bsb[kk*BSTR + tx*4 + j];
#pragma unroll
            for (int i = 0; i < 8; ++i)
#pragma unroll
                for (int j = 0; j < 4; ++j)
                    acc[i][j] = fmaf(a[i], b[j], acc[i][j]);
        }
        if (t < 47) {
#pragma unroll
            for (int j = 0; j < 4; ++j) {
                As[cur^1][(ak+j)*ASTR + am]   = ((const float*)&a0)[j];
                As[cur^1][(ak+4+j)*ASTR + am] = ((const float*)&a1)[j];
                Bs[cur^1][(bk+j)*BSTR + bnr]  = ((const float*)&bv)[j];
            }
        }
        __syncthreads();
    }

    // epilogue scatter (block-uniform region)
    const int colbase = bn*64 + tx*4;
    if (colbase < 768) {
#pragma unroll
        for (int i = 0; i < 8; ++i) {
            const int trow = bm*128 + ty*8 + i;
            float4 o = {acc[i][0], acc[i][1], acc[i][2], acc[i][3]};
            *(float4*)(qtok + (size_t)trow*768 + colbase) = o;
        }
    } else if (colbase < 1536) {
        const int p = colbase - 768;                  // h*64+d
#pragma unroll
        for (int i = 0; i < 8; ++i) {
            const int trow = bm*128 + ty*8 + i;
            const int b = trow >> 10, n = trow & 1023;
#pragma unroll
            for (int j = 0; j < 4; ++j)
                kt[((size_t)(b*768 + p + j))*NN + n] = acc[i][j];
        }
    } else {
        const int p = colbase - 1536;                 // h = p>>6, d = p&63 (4-aligned)
#pragma unroll
        for (int i = 0; i < 8; ++i) {
            const int trow = bm*128 + ty*8 + i;
            const int b = trow >> 10, n = trow & 1023;
            float4 o = {acc[i][0], acc[i][1], acc[i][2], acc[i][3]};
            *(float4*)(vws + (((size_t)b*HH + (p >> 6))*NN + n)*HD + (p & 63)) = o;
        }
    }
}

// ---------------------------------------------------------------------------
// Kernel 2: per block = 2 consecutive tokens; one K float4 load feeds both
// tokens' logits.  XCD pinning keeps one batch's K per XCD L2.
// launch_bounds relaxed to (256,2): l0/l1 (96 floats) stay in arch VGPRs.
// ---------------------------------------------------------------------------
__global__ __launch_bounds__(256, 2)
void attn_expand(const float* __restrict__ qtok, const float* __restrict__ kt,
                 const float* __restrict__ Wexp, float* __restrict__ aexp)
{
    __shared__ __align__(16) float qs[2*CC];
    __shared__ float wexp_s[HPP * HH];
    __shared__ float smax[2][HH * 4];
    __shared__ float ssum[2][HH * 4];

    const int tid  = threadIdx.x;
    const int lane = tid & 63, wid = tid >> 6;
    const int x    = blockIdx.x & 7;
    const int b    = x >> 2;
    const int np   = ((x & 3) << 7) | (blockIdx.x >> 3);
    const int n0   = np << 1;
    const int m4   = tid;

    const fvec4* qsrc = (const fvec4*)(qtok + (size_t)(b*NN + n0) * CC);
    ((fvec4*)qs)[tid] = qsrc[tid];
    if (tid < 128) ((fvec4*)qs)[256 + tid] = qsrc[256 + tid];
    for (int i2 = tid; i2 < HPP*HH; i2 += 256) wexp_s[i2] = Wexp[i2];
    __syncthreads();

    fvec4 l0[HH], l1[HH];
#pragma unroll
    for (int h = 0; h < HH; ++h) {
        fvec4 a0 = {0.f,0.f,0.f,0.f}, a1 = {0.f,0.f,0.f,0.f};
        const fvec4* kr = ((const fvec4*)kt) + (size_t)(b*768 + h*64) * 256 + m4;
        const float* q0p = qs + h*64;
        const float* q1p = qs + CC + h*64;
#pragma unroll 8
        for (int d = 0; d < 64; ++d) {
            const fvec4 kv = kr[(size_t)d * 256];
            const float qa = q0p[d];
            const float qb = q1p[d];
            a0.x = fmaf(kv.x, qa, a0.x); a0.y = fmaf(kv.y, qa, a0.y);
            a0.z = fmaf(kv.z, qa, a0.z); a0.w = fmaf(kv.w, qa, a0.w);
            a1.x = fmaf(kv.x, qb, a1.x); a1.y = fmaf(kv.y, qb, a1.y);
            a1.z = fmaf(kv.z, qb, a1.z); a1.w = fmaf(kv.w, qb, a1.w);
        }
        l0[h].x = a0.x*SCALE; l0[h].y = a0.y*SCALE;
        l0[h].z = a0.z*SCALE; l0[h].w = a0.w*SCALE;
        l1[h].x = a1.x*SCALE; l1[h].y = a1.y*SCALE;
        l1[h].z = a1.z*SCALE; l1[h].w = a1.w*SCALE;
    }

#pragma unroll
    for (int h = 0; h < HH; ++h) {
        float t0 = fmaxf(fmaxf(l0[h].x, l0[h].y), fmaxf(l0[h].z, l0[h].w));
        float t1 = fmaxf(fmaxf(l1[h].x, l1[h].y), fmaxf(l1[h].z, l1[h].w));
#pragma unroll
        for (int off = 32; off > 0; off >>= 1) {
            t0 = fmaxf(t0, __shfl_xor(t0, off, 64));
            t1 = fmaxf(t1, __shfl_xor(t1, off, 64));
        }
        if (lane == 0) { smax[0][h*4 + wid] = t0; smax[1][h*4 + wid] = t1; }
    }
    __syncthreads();

#pragma unroll
    for (int h = 0; h < HH; ++h) {
        const float m0 = fmaxf(fmaxf(smax[0][h*4+0], smax[0][h*4+1]),
                               fmaxf(smax[0][h*4+2], smax[0][h*4+3]));
        const float m1 = fmaxf(fmaxf(smax[1][h*4+0], smax[1][h*4+1]),
                               fmaxf(smax[1][h*4+2], smax[1][h*4+3]));
        l0[h].x = __expf(l0[h].x - m0); l0[h].y = __expf(l0[h].y - m0);
        l0[h].z = __expf(l0[h].z - m0); l0[h].w = __expf(l0[h].w - m0);
        l1[h].x = __expf(l1[h].x - m1); l1[h].y = __expf(l1[h].y - m1);
        l1[h].z = __expf(l1[h].z - m1); l1[h].w = __expf(l1[h].w - m1);
        float s0 = (l0[h].x + l0[h].y) + (l0[h].z + l0[h].w);
        float s1 = (l1[h].x + l1[h].y) + (l1[h].z + l1[h].w);
#pragma unroll
        for (int off = 32; off > 0; off >>= 1) {
            s0 += __shfl_xor(s0, off, 64);
            s1 += __shfl_xor(s1, off, 64);
        }
        if (lane == 0) { ssum[0][h*4 + wid] = s0; ssum[1][h*4 + wid] = s1; }
    }
    __syncthreads();

#pragma unroll
    for (int h = 0; h < HH; ++h) {
        const float i0 = 1.f / (ssum[0][h*4+0] + ssum[0][h*4+1] +
                                ssum[0][h*4+2] + ssum[0][h*4+3]);
        const float i1 = 1.f / (ssum[1][h*4+0] + ssum[1][h*4+1] +
                                ssum[1][h*4+2] + ssum[1][h*4+3]);
        l0[h].x *= i0; l0[h].y *= i0; l0[h].z *= i0; l0[h].w *= i0;
        l1[h].x *= i1; l1[h].y *= i1; l1[h].z *= i1; l1[h].w *= i1;
    }

    fvec4* ab = ((fvec4*)aexp) + ((size_t)b*HPP*NN + n0) * 256;
#pragma unroll 4
    for (int o = 0; o < HPP; ++o) {
        fvec4 e0 = {0.f,0.f,0.f,0.f}, e1 = {0.f,0.f,0.f,0.f};
#pragma unroll
        for (int h = 0; h < HH; ++h) {
            const float w = wexp_s[o*HH + h];
            e0.x = fmaf(w, l0[h].x, e0.x); e0.y = fmaf(w, l0[h].y, e0.y);
            e0.z = fmaf(w, l0[h].z, e0.z); e0.w = fmaf(w, l0[h].w, e0.w);
            e1.x = fmaf(w, l1[h].x, e1.x); e1.y = fmaf(w, l1[h].y, e1.y);
            e1.z = fmaf(w, l1[h].z, e1.z); e1.w = fmaf(w, l1[h].w, e1.w);
        }
        fvec4* p0 = ab + (size_t)o * NN * 256 + m4;
        __builtin_nontemporal_store(e0, p0);
        __builtin_nontemporal_store(e1, p0 + 256);
    }
}

// ---------------------------------------------------------------------------
// Kernel 3: 512 threads, 2 tokens per block (half-block per token).
// Conv register-resident; column taps via __shfl; no barriers in channel
// loop; zero bank conflicts.  launch_bounds relaxed to (512,2) so the
// ~94 live floats stay in arch VGPRs (no AGPR/scratch shuffling).
// PV: each V float4 feeds BOTH tokens.
// ---------------------------------------------------------------------------
__global__ __launch_bounds__(512, 2)
void conv_red_pv(const float* __restrict__ aexp, const float* __restrict__ Wloc,
                 const float* __restrict__ bloc, const float* __restrict__ Wred,
                 const float* __restrict__ vws, float* __restrict__ hout)
{
    __shared__ __align__(16) float probs[8][NN];   // 32 KB
    __shared__ float redbuf[2][HH][4];

    const int tid  = threadIdx.x;
    const int lane = tid & 63;
    const int w    = tid >> 6;          // wave 0..7
    const int tk   = w >> 2;            // token within pair
    const int wq   = w & 3;             // m-chunk within half-block
    const int t    = tid & 255;         // m float4 index 0..255

    const int x  = blockIdx.x & 7;      // XCD slot
    const int b  = x >> 2;
    const int np = ((x & 3) << 7) | (blockIdx.x >> 3);
    const int n0 = np << 1;
    const int n  = n0 + tk;

    const bool rv0 = n > 0, rv2 = n < NN - 1;

    float4 acc[HH];
#pragma unroll
    for (int i = 0; i < HH; ++i) acc[i] = make_float4(0.f,0.f,0.f,0.f);

    auto loadch = [&](int o, float4 ld[3], float hl[3], float hr[3]) {
        const float* cb = aexp + ((size_t)(b*HPP + o) * NN + (size_t)(n-1)) * NN;
#pragma unroll
        for (int r = 0; r < 3; ++r) {
            const bool ok = (r == 0) ? rv0 : (r == 2 ? rv2 : true);
            const float* rp = cb + (size_t)r * NN;
            if (ok) {
                ld[r] = ((const float4*)rp)[t];
                hl[r] = (lane == 0  && wq > 0) ? rp[4*t - 1] : 0.f;
                hr[r] = (lane == 63 && wq < 3) ? rp[4*t + 4] : 0.f;
            } else {
                ld[r] = make_float4(0.f,0.f,0.f,0.f);
                hl[r] = 0.f; hr[r] = 0.f;
            }
        }
    };

    float4 ld[3]; float hl[3], hr[3];
    loadch(0, ld, hl, hr);

    for (int o = 0; o < HPP; ++o) {
        float4 l2[3]; float h2l[3], h2r[3];
        if (o < HPP-1) loadch(o+1, l2, h2l, h2r);

        const float* wl = Wloc + o*9;
        const float  bb = bloc[o];
        float v0 = bb, v1 = bb, v2 = bb, v3 = bb;
#pragma unroll
        for (int r = 0; r < 3; ++r) {
            const float w0 = wl[r*3+0], w1 = wl[r*3+1], w2 = wl[r*3+2];
            const float4 c = ld[r];
            float lf = __shfl_up(c.w, 1, 64);
            float rt = __shfl_down(c.x, 1, 64);
            if (lane == 0)  lf = hl[r];
            if (lane == 63) rt = hr[r];
            v0 = fmaf(w0, lf,  v0); v0 = fmaf(w1, c.x, v0); v0 = fmaf(w2, c.y, v0);
            v1 = fmaf(w0, c.x, v1); v1 = fmaf(w1, c.y, v1); v1 = fmaf(w2, c.z, v1);
            v2 = fmaf(w0, c.y, v2); v2 = fmaf(w1, c.z, v2); v2 = fmaf(w2, c.w, v2);
            v3 = fmaf(w0, c.z, v3); v3 = fmaf(w1, c.w, v3); v3 = fmaf(w2, rt,  v3);
        }
        v0 = fmaxf(v0, 0.f); v1 = fmaxf(v1, 0.f);
        v2 = fmaxf(v2, 0.f); v3 = fmaxf(v3, 0.f);
#pragma unroll
        for (int i = 0; i < HH; ++i) {
            const float wr = Wred[i*HPP + o];
            acc[i].x = fmaf(wr, v0, acc[i].x);
            acc[i].y = fmaf(wr, v1, acc[i].y);
            acc[i].z = fmaf(wr, v2, acc[i].z);
            acc[i].w = fmaf(wr, v3, acc[i].w);
        }
        if (o < HPP-1) {
#pragma unroll
            for (int r = 0; r < 3; ++r) { ld[r]=l2[r]; hl[r]=h2l[r]; hr[r]=h2r[r]; }
        }
    }
#pragma unroll
    for (int i = 0; i < HH; ++i) {
        acc[i].x *= SCALE; acc[i].y *= SCALE;
        acc[i].z *= SCALE; acc[i].w *= SCALE;
    }

#pragma unroll
    for (int i = 0; i < HH; ++i) {
        float tm = fmaxf(fmaxf(acc[i].x, acc[i].y), fmaxf(acc[i].z, acc[i].w));
#pragma unroll
        for (int off = 32; off > 0; off >>= 1) tm = fmaxf(tm, __shfl_xor(tm, off, 64));
        if (lane == 0) redbuf[tk][i][wq] = tm;
    }
    __syncthreads();
    float mh[HH];
#pragma unroll
    for (int i = 0; i < HH; ++i)
        mh[i] = fmaxf(fmaxf(redbuf[tk][i][0], redbuf[tk][i][1]),
                      fmaxf(redbuf[tk][i][2], redbuf[tk][i][3]));
    __syncthreads();

#pragma unroll
    for (int i = 0; i < HH; ++i) {
        acc[i].x = __expf(acc[i].x - mh[i]);
        acc[i].y = __expf(acc[i].y - mh[i]);
        acc[i].z = __expf(acc[i].z - mh[i]);
        acc[i].w = __expf(acc[i].w - mh[i]);
        float s = (acc[i].x + acc[i].y) + (acc[i].z + acc[i].w);
#pragma unroll
        for (int off = 32; off > 0; off >>= 1) s += __shfl_xor(s, off, 64);
        if (lane == 0) redbuf[tk][i][wq] = s;
    }
    __syncthreads();
#pragma unroll
    for (int i = 0; i < HH; ++i) {
        const float inv = 1.f / (redbuf[tk][i][0] + redbuf[tk][i][1] +
                                 redbuf[tk][i][2] + redbuf[tk][i][3]);
        acc[i].x *= inv; acc[i].y *= inv; acc[i].z *= inv; acc[i].w *= inv;
    }

    const int hq = w >> 1;
    const int dh = w & 1;
    const int mg = lane >> 3;
    const int dq = lane & 7;

    for (int g = 0; g < 3; ++g) {
        __syncthreads();
#pragma unroll
        for (int q2 = 0; q2 < 4; ++q2)
            ((float4*)&probs[q2*2 + tk][0])[t] = acc[4*g + q2];
        __syncthreads();

        const int h = 4*g + hq;
        const float4* vp = ((const float4*)vws)
                         + ((size_t)(b*HH + h) * NN) * 16 + dh*8 + dq;
        const float* p0 = &probs[hq*2 + 0][0] + mg;
        const float* p1 = &probs[hq*2 + 1][0] + mg;
        float4 a0 = make_float4(0.f,0.f,0.f,0.f);
        float4 a1 = make_float4(0.f,0.f,0.f,0.f);
#pragma unroll 8
        for (int m0 = 0; m0 < NN; m0 += 8) {
            const float  pa = p0[m0];
            const float  pb = p1[m0];
            const float4 vv = vp[(size_t)(m0 + mg) * 16];
            a0.x = fmaf(pa, vv.x, a0.x); a0.y = fmaf(pa, vv.y, a0.y);
            a0.z = fmaf(pa, vv.z, a0.z); a0.w = fmaf(pa, vv.w, a0.w);
            a1.x = fmaf(pb, vv.x, a1.x); a1.y = fmaf(pb, vv.y, a1.y);
            a1.z = fmaf(pb, vv.z, a1.z); a1.w = fmaf(pb, vv.w, a1.w);
        }
#pragma unroll
        for (int off = 8; off < 64; off <<= 1) {
            a0.x += __shfl_xor(a0.x, off, 64); a0.y += __shfl_xor(a0.y, off, 64);
            a0.z += __shfl_xor(a0.z, off, 64); a0.w += __shfl_xor(a0.w, off, 64);
            a1.x += __shfl_xor(a1.x, off, 64); a1.y += __shfl_xor(a1.y, off, 64);
            a1.z += __shfl_xor(a1.z, off, 64); a1.w += __shfl_xor(a1.w, off, 64);
        }
        if (mg == 0) {
            ((float4*)(hout + ((size_t)(b*NN + n0    ) * CC) + h*HD))[dh*8 + dq] = a0;
            ((float4*)(hout + ((size_t)(b*NN + n0 + 1) * CC) + h*HD))[dh*8 + dq] = a1;
        }
    }
}

// ---------------------------------------------------------------------------
// Kernel 4: final projection  out = head_out @ Wproj^T + bias
// Same 128x64 double-buffered structure as qkv_gemm.
// ---------------------------------------------------------------------------
__global__ __launch_bounds__(256)
void proj_gemm(const float* __restrict__ A, const float* __restrict__ Wp,
               const float* __restrict__ bias, float* __restrict__ out)
{
    __shared__ float As[2][16*ASTR];
    __shared__ float Bs[2][16*BSTR];

    const int tid = threadIdx.x;
    const int bn  = blockIdx.x;            // 0..11
    const int bm  = blockIdx.y;            // 0..15
    const int tx  = tid & 15, ty = tid >> 4;

    const int am  = tid >> 1, ak = (tid & 1) * 8;
    const int bnr = tid >> 2, bk = (tid & 3) * 4;

    const float* Ap = A  + (size_t)(bm*128 + am) * 768 + ak;
    const float* Bp = Wp + (size_t)(bn*64 + bnr) * 768 + bk;

    float acc[8][4] = {};

    float4 a0 = *(const float4*)(Ap);
    float4 a1 = *(const float4*)(Ap + 4);
    float4 bv = *(const float4*)(Bp);
#pragma unroll
    for (int j = 0; j < 4; ++j) {
        As[0][(ak+j)*ASTR + am]   = ((const float*)&a0)[j];
        As[0][(ak+4+j)*ASTR + am] = ((const float*)&a1)[j];
        Bs[0][(bk+j)*BSTR + bnr]  = ((const float*)&bv)[j];
    }
    __syncthreads();

    for (int t = 0; t < 48; ++t) {
        const int cur = t & 1;
        if (t < 47) {
            a0 = *(const float4*)(Ap + (t+1)*16);
            a1 = *(const float4*)(Ap + (t+1)*16 + 4);
            bv = *(const float4*)(Bp + (t+1)*16);
        }
        const float* Asb = As[cur];
        const float* Bsb = Bs[cur];
#pragma unroll
        for (int kk = 0; kk < 16; ++kk) {
            float a[8], b[4];
#pragma unroll
            for (int i = 0; i < 8; ++i) a[i] = Asb[kk*ASTR + ty*8 + i];
#pragma unroll
            for (int j = 0; j < 4; ++j) b[j] = Bsb[kk*BSTR + tx*4 + j];
#pragma unroll
            for (int i = 0; i < 8; ++i)
#pragma unroll
                for (int j = 0; j < 4; ++j)
                    acc[i][j] = fmaf(a[i], b[j], acc[i][j]);
        }
        if (t < 47) {
#pragma unroll
            for (int j = 0; j < 4; ++j) {
                As[cur^1][(ak+j)*ASTR + am]   = ((const float*)&a0)[j];
                As[cur^1][(ak+4+j)*ASTR + am] = ((const float*)&a1)[j];
                Bs[cur^1][(bk+j)*BSTR + bnr]  = ((const float*)&bv)[j];
            }
        }
        __syncthreads();
    }

    const int colbase = bn*64 + tx*4;
    const float4 bb = *(const float4*)(bias + colbase);
#pragma unroll
    for (int i = 0; i < 8; ++i) {
        const int trow = bm*128 + ty*8 + i;
        float4 o = {acc[i][0] + bb.x, acc[i][1] + bb.y,
                    acc[i][2] + bb.z, acc[i][3] + bb.w};
        *(float4*)(out + (size_t)trow*768 + colbase) = o;
    }
}

// ---------------------------------------------------------------------------
extern "C" void kernel_launch(void* const* d_in, const int* in_sizes, int n_in,
                              void* d_out, int out_size, void* d_ws, size_t ws_size,
                              hipStream_t stream)
{
    const float* x     = (const float*)d_in[0];
    const float* Wqk   = (const float*)d_in[1];
    const float* Wv    = (const float*)d_in[2];
    const float* Wexp  = (const float*)d_in[3];
    const float* Wloc  = (const float*)d_in[4];
    const float* bloc  = (const float*)d_in[5];
    const float* Wred  = (const float*)d_in[6];
    const float* Wproj = (const float*)d_in[7];
    const float* bproj = (const float*)d_in[8];

    float* out  = (float*)d_out;              // (B,N,C)
    float* aexp = out + (size_t)SEG;          // (B,HP,N,N)
    float* ws   = (float*)d_ws;

    qkv_gemm   <<<dim3(36, 16), 256, 0, stream>>>(x, Wqk, Wv, ws);
    attn_expand<<<dim3(BB * NN / 2), 256, 0, stream>>>(ws + QOFF, ws + KOFF, Wexp, aexp);
    conv_red_pv<<<dim3(BB * NN / 2), 512, 0, stream>>>(aexp, Wloc, bloc, Wred,
                                                       ws + VOFF, ws + HOFF);
    proj_gemm  <<<dim3(12, 16), 256, 0, stream>>>(ws + HOFF, Wproj, bproj, out);
}